// Round 18
// baseline (91.946 us; speedup 1.0000x reference)
//
#include <hip/hip_runtime.h>

typedef __attribute__((ext_vector_type(8))) _Float16 f16x8;
typedef __attribute__((ext_vector_type(4))) float f32x4;

#define HSTR 264   // fp16 per A/C row (528B): 16B-aligned, staggered banks

// ---- prep: weights -> fp16, fragment-contiguous (lane-major) into d_ws ----
__global__ __launch_bounds__(256) void prep_kernel(
    const float* __restrict__ gW0, const float* __restrict__ gW1,
    _Float16* __restrict__ W0c, _Float16* __restrict__ W1c)
{
  const int t = blockIdx.x * 256 + threadIdx.x;  // 0..65535
  {
    const int c = t >> 7, k = t & 127;           // c in [0,512), k in [0,128)
    const int dst = ((k >> 5) * 32 + (c >> 4)) * 512 +
                    (((k >> 3) & 3) * 16 + (c & 15)) * 8 + (k & 7);
    const int src = (k + ((c >= 256) ? 128 : 0)) * 256 + (c & 255);
    W0c[dst] = (_Float16)gW0[src];
  }
  {
    const int n = t >> 8, k = t & 255;           // n in [0,256), k in [0,256)
    const int dst = ((k >> 5) * 16 + (n >> 4)) * 512 +
                    (((k >> 3) & 3) * 16 + (n & 15)) * 8 + (k & 7);
    W1c[dst] = (_Float16)gW1[k * 256 + n];
  }
}

// ---- main: N-split=4 x M-split=2, all-u-in-LDS, 128-AGPR weights ----
// r15 budget: LDS consume 20us (u read 8x, once per N-split), MFMA 17.6us,
// VALU 13us. This round halves N-splits: wave w owns 64 N-cols (bw[4][8] =
// 128 AGPRs, r11-precedented spill-free at waves_per_eu=2) and consumes only
// its M-half (waves 0-3: tiles 0-7; waves 4-7: tiles 8-15) -> LDS reads
// halve to 512KB/block. One 512-thread block/CU (LDS 139KB), wpe=2 budget
// 256 regs/wave: 128 AGPR + ~100 VGPR fits (r14's spill was 320>128 budget;
// this is 228<256). No round structure: produce ALL 16 u-tiles (2/wave),
// ONE barrier, consume 8 tiles/wave barrier-free (4 indep MFMA chains/tile).
__global__ __launch_bounds__(512, 2) void pair_kernel(
    const float* __restrict__ state,
    const _Float16* __restrict__ W0c, const float* __restrict__ gb0,
    const _Float16* __restrict__ W1c, const float* __restrict__ gb1,
    float* __restrict__ pooled)
{
  const int b   = blockIdx.x;
  const int tid = threadIdx.x;
  const int w   = tid >> 6;   // wave 0..7
  const int l   = tid & 63;
  const int lr  = l & 15;
  const int lg  = l >> 4;

  // [0, 8448) A_lds f16 [16][HSTR]; [8448, +131072) ubuf: 16 x 8KB u-tiles
  // (C staged at ubuf start first; 2KB pooled pool reuses ubuf at the end)
  __shared__ __align__(16) char smem[8448 + 131072];
  _Float16* A_lds = (_Float16*)smem;
  char*     ubuf  = smem + 8448;
  _Float16* C_st  = (_Float16*)ubuf;   // staging overlay, dead after creg capture

  const float* stb = state + (size_t)b * 2048;

  // ---------------- Phase 2: [A|C] = state[16x128] @ W0 (fp16 MFMA) ----------------
  f16x8 sfrag[4];
  #pragma unroll
  for (int kk = 0; kk < 4; ++kk) {
    const float* sp = stb + lr * 128 + kk * 32 + lg * 8;
    f32x4 s0 = *(const f32x4*)sp;
    f32x4 s1 = *(const f32x4*)(sp + 4);
    f16x8 f;
    f[0] = (_Float16)s0[0]; f[1] = (_Float16)s0[1];
    f[2] = (_Float16)s0[2]; f[3] = (_Float16)s0[3];
    f[4] = (_Float16)s1[0]; f[5] = (_Float16)s1[1];
    f[6] = (_Float16)s1[2]; f[7] = (_Float16)s1[3];
    sfrag[kk] = f;
  }

  const f32x4 z4 = {0.f, 0.f, 0.f, 0.f};
  f32x4 acc2[4];
  #pragma unroll
  for (int nt = 0; nt < 4; ++nt) acc2[nt] = z4;

  // wave w owns [A|C] cols [64w, 64w+64) for phase 2
  #pragma unroll
  for (int nt = 0; nt < 4; ++nt) {
    #pragma unroll
    for (int kk = 0; kk < 4; ++kk) {
      f16x8 bf = *(const f16x8*)(W0c + (size_t)((kk * 32 + 4 * w + nt) * 512 + l * 8));
      acc2[nt] = __builtin_amdgcn_mfma_f32_16x16x32_f16(sfrag[kk], bf, acc2[nt], 0, 0, 0);
    }
  }

  // W1 fragments: wave w owns N-cols [64*(w&3), +64) -> 4nt x 8kk = 128 AGPRs
  // (pin precedented r11: (.,2) budget 256, no remat, no spill)
  const int n4 = w & 3;
  f16x8 bw[4][8];
  #pragma unroll
  for (int nt = 0; nt < 4; ++nt) {
    #pragma unroll
    for (int kk = 0; kk < 8; ++kk) {
      bw[nt][kk] = *(const f16x8*)(W1c + (size_t)((kk * 16 + 4 * n4 + nt) * 512 + l * 8));
      asm volatile("" : "+a"(bw[nt][kk]));   // park in AGPR
    }
  }
  float gb1v[4];
  #pragma unroll
  for (int nt = 0; nt < 4; ++nt) gb1v[nt] = gb1[64 * n4 + 16 * nt + lr];

  // store phase-2 results as fp16 (C/D layout: col=lr, row=lg*4+r); fold gb0
  #pragma unroll
  for (int nt = 0; nt < 4; ++nt) {
    const int col = 64 * w + 16 * nt + lr;
    #pragma unroll
    for (int r = 0; r < 4; ++r) {
      const int row = lg * 4 + r;
      const float v = acc2[nt][r];
      if (col < 256) A_lds[row * HSTR + col]       = (_Float16)(v + gb0[col]);
      else           C_st[row * HSTR + col - 256]  = (_Float16)v;
    }
  }
  __syncthreads();

  // creg: full k for this lane's C row: lane (lr,lg) holds C[lr][kk*32+lg*8..+8]
  f16x8 creg[8];
  #pragma unroll
  for (int kk = 0; kk < 8; ++kk)
    creg[kk] = *(const f16x8*)&C_st[lr * HSTR + kk * 32 + lg * 8];
  __syncthreads();   // C_st dead; ubuf writable

  const f16x8 zh = {(_Float16)0, (_Float16)0, (_Float16)0, (_Float16)0,
                    (_Float16)0, (_Float16)0, (_Float16)0, (_Float16)0};

  // ---- produce: wave w builds tiles 2w and 2w+1 (full k), lane-linear ----
  #pragma unroll
  for (int tt = 0; tt < 2; ++tt) {
    const int ip = 2 * w + tt;
    char* tb = ubuf + ip * 8192;
    #pragma unroll
    for (int kk = 0; kk < 8; ++kk) {
      f16x8 av = *(const f16x8*)&A_lds[ip * HSTR + kk * 32 + lg * 8];  // bcast
      f16x8 u = __builtin_elementwise_max(av + creg[kk], zh);
      *(f16x8*)(tb + kk * 1024 + l * 16) = u;
    }
  }
  __syncthreads();   // all 16 u-tiles ready

  // ---- consume: this wave's M-half (8 tiles), 64 N-cols, barrier-free ----
  const int mg = w >> 2;   // 0: tiles 0-7, 1: tiles 8-15
  float pp[4] = {0.f, 0.f, 0.f, 0.f};
  #pragma unroll 2
  for (int t8 = 0; t8 < 8; ++t8) {
    const int i = 8 * mg + t8;
    const char* tb = ubuf + i * 8192;
    f32x4 acc[4];
    #pragma unroll
    for (int nt = 0; nt < 4; ++nt) acc[nt] = z4;
    #pragma unroll
    for (int kk = 0; kk < 8; ++kk) {
      f16x8 uf = *(const f16x8*)(tb + kk * 1024 + l * 16);  // linear sweep
      #pragma unroll
      for (int nt = 0; nt < 4; ++nt)
        acc[nt] = __builtin_amdgcn_mfma_f32_16x16x32_f16(uf, bw[nt][kk], acc[nt], 0, 0, 0);
    }
    #pragma unroll
    for (int nt = 0; nt < 4; ++nt) {
      #pragma unroll
      for (int r = 0; r < 4; ++r) {
        const int row = lg * 4 + r;       // = j
        const float v = fmaxf(acc[nt][r] + gb1v[nt], 0.f);
        pp[nt] += (row == i) ? 0.f : v;   // mask the (i,i) filler pair
      }
    }
  }
  __syncthreads();   // ubuf consumed everywhere; pool may overwrite

  // ---- pooled reduce: lane groups -> pool[2][256] -> sum M-halves ----
  float* pool = (float*)ubuf;
  #pragma unroll
  for (int nt = 0; nt < 4; ++nt) {
    float v = pp[nt];
    v += __shfl_xor(v, 16);
    v += __shfl_xor(v, 32);
    if (lg == 0) pool[mg * 256 + 64 * n4 + 16 * nt + lr] = v;
  }
  __syncthreads();
  if (tid < 256)
    pooled[(size_t)b * 256 + tid] = pool[tid] + pool[256 + tid];
}

// ---- f-MLP: 256 blocks x 4 batches (all CUs busy; weights L2-resident) ----
__global__ __launch_bounds__(256) void fmlp_kernel(
    const float* __restrict__ pooled,
    const float* __restrict__ fW0, const float* __restrict__ fb0,
    const float* __restrict__ fW1, const float* __restrict__ fb1,
    float* __restrict__ out)
{
  const int tid = threadIdx.x;
  const size_t b0 = (size_t)blockIdx.x * 4;
  __shared__ float pl[4][256];
  __shared__ float h1[4][256];

  #pragma unroll
  for (int q = 0; q < 4; ++q)
    pl[q][tid] = pooled[(b0 + q) * 256 + tid];
  __syncthreads();

  float acc[4] = {0.f, 0.f, 0.f, 0.f};
  #pragma unroll 8
  for (int k = 0; k < 256; ++k) {
    const float wv = fW0[(size_t)k * 256 + tid];
    #pragma unroll
    for (int q = 0; q < 4; ++q) acc[q] = fmaf(pl[q][k], wv, acc[q]);
  }
  #pragma unroll
  for (int q = 0; q < 4; ++q) h1[q][tid] = fmaxf(acc[q] + fb0[tid], 0.f);
  __syncthreads();

  float acc2[4] = {0.f, 0.f, 0.f, 0.f};
  #pragma unroll 8
  for (int k = 0; k < 256; ++k) {
    const float wv = fW1[(size_t)k * 256 + tid];
    #pragma unroll
    for (int q = 0; q < 4; ++q) acc2[q] = fmaf(h1[q][k], wv, acc2[q]);
  }
  #pragma unroll
  for (int q = 0; q < 4; ++q)
    out[(b0 + q) * 256 + tid] = fmaxf(acc2[q] + fb1[tid], 0.f);
}

extern "C" void kernel_launch(void* const* d_in, const int* in_sizes, int n_in,
                              void* d_out, int out_size, void* d_ws, size_t ws_size,
                              hipStream_t stream) {
  const float* state = (const float*)d_in[0];
  const float* gW0   = (const float*)d_in[1];
  const float* gb0   = (const float*)d_in[2];
  const float* gW1   = (const float*)d_in[3];
  const float* gb1   = (const float*)d_in[4];
  const float* fW0   = (const float*)d_in[5];
  const float* fb0   = (const float*)d_in[6];
  const float* fW1   = (const float*)d_in[7];
  const float* fb1   = (const float*)d_in[8];
  float* out = (float*)d_out;

  _Float16* W0c = (_Float16*)d_ws;                      // 65536 fp16 = 128KB
  _Float16* W1c = W0c + 65536;                          // 65536 fp16 = 128KB
  float* pooled = (float*)(W1c + 65536);                // 1024*256 f32 = 1MB

  const int Bn = in_sizes[0] / 2048;  // 1024

  prep_kernel<<<dim3(256), dim3(256), 0, stream>>>(gW0, gW1, W0c, W1c);
  pair_kernel<<<dim3(Bn), dim3(512), 0, stream>>>(state, W0c, gb0, W1c, gb1, pooled);
  fmlp_kernel<<<dim3(Bn / 4), dim3(256), 0, stream>>>(pooled, fW0, fb0, fW1, fb1, out);
}

// Round 19
// 72.485 us; speedup vs baseline: 1.2685x; 1.2685x over previous
//
#include <hip/hip_runtime.h>

typedef __attribute__((ext_vector_type(8))) _Float16 f16x8;
typedef __attribute__((ext_vector_type(4))) float f32x4;

#define HSTR 264   // fp16 per A/C row (528B): 16B-aligned, staggered banks

// ---- prep: weights -> fp16, fragment-contiguous (lane-major) into d_ws ----
__global__ __launch_bounds__(256) void prep_kernel(
    const float* __restrict__ gW0, const float* __restrict__ gW1,
    _Float16* __restrict__ W0c, _Float16* __restrict__ W1c)
{
  const int t = blockIdx.x * 256 + threadIdx.x;  // 0..65535
  {
    const int c = t >> 7, k = t & 127;           // c in [0,512), k in [0,128)
    const int dst = ((k >> 5) * 32 + (c >> 4)) * 512 +
                    (((k >> 3) & 3) * 16 + (c & 15)) * 8 + (k & 7);
    const int src = (k + ((c >= 256) ? 128 : 0)) * 256 + (c & 255);
    W0c[dst] = (_Float16)gW0[src];
  }
  {
    const int n = t >> 8, k = t & 255;           // n in [0,256), k in [0,256)
    const int dst = ((k >> 5) * 16 + (n >> 4)) * 512 +
                    (((k >> 3) & 3) * 16 + (n & 15)) * 8 + (k & 7);
    W1c[dst] = (_Float16)gW1[k * 256 + n];
  }
}

// ---- main: r15 core + double-buffer ONLY (consume unchanged) ----
// Occupancy evidence r4/r11/r15/r18: time tracks waves/SIMD (1->121us,
// 2->66-78us, 4->55-57us); r15's 64AGPR+64VGPR @ (512,4) = the max-interleave
// operating point. Remaining slack: 8 lockstep barriers/batch. This round:
// produce tile-set g+1 into the other 32KB buffer BEFORE consuming set g --
// one barrier per round (8->5), produce VALU/ds_write hides under consume
// MFMA (separate pipes). Consume is exactly r15's (sequential tiles, 2
// chains) -- r16's spill was the paired-consume +12 VGPRs, not the dbuf.
__global__ __launch_bounds__(512, 4) void pair_kernel(
    const float* __restrict__ state,
    const _Float16* __restrict__ W0c, const float* __restrict__ gb0,
    const _Float16* __restrict__ W1c, const float* __restrict__ gb1,
    float* __restrict__ pooled)
{
  const int b   = blockIdx.x;
  const int tid = threadIdx.x;
  const int w   = tid >> 6;   // wave 0..7
  const int l   = tid & 63;
  const int lr  = l & 15;
  const int lg  = l >> 4;

  // [0,8448) A_lds; [8448,+32K) buf0; [+32K,+64K) buf1 (C staged in buf1)
  __shared__ __align__(16) char smem[8448 + 65536];
  _Float16* A_lds = (_Float16*)smem;
  char*     buf0  = smem + 8448;
  char*     buf1  = buf0 + 32768;
  _Float16* C_st  = (_Float16*)buf1;   // staging overlay, dead after creg capture

  const float* stb = state + (size_t)b * 2048;

  // ---------------- Phase 2: [A|C] = state[16x128] @ W0 (fp16 MFMA) ----------------
  f16x8 sfrag[4];
  #pragma unroll
  for (int kk = 0; kk < 4; ++kk) {
    const float* sp = stb + lr * 128 + kk * 32 + lg * 8;
    f32x4 s0 = *(const f32x4*)sp;
    f32x4 s1 = *(const f32x4*)(sp + 4);
    f16x8 f;
    f[0] = (_Float16)s0[0]; f[1] = (_Float16)s0[1];
    f[2] = (_Float16)s0[2]; f[3] = (_Float16)s0[3];
    f[4] = (_Float16)s1[0]; f[5] = (_Float16)s1[1];
    f[6] = (_Float16)s1[2]; f[7] = (_Float16)s1[3];
    sfrag[kk] = f;
  }

  const f32x4 z4 = {0.f, 0.f, 0.f, 0.f};
  f32x4 acc2[4];
  #pragma unroll
  for (int nt = 0; nt < 4; ++nt) acc2[nt] = z4;

  // wave w owns [A|C] cols [64w, 64w+64) for phase 2
  #pragma unroll
  for (int nt = 0; nt < 4; ++nt) {
    #pragma unroll
    for (int kk = 0; kk < 4; ++kk) {
      f16x8 bf = *(const f16x8*)(W0c + (size_t)((kk * 32 + 4 * w + nt) * 512 + l * 8));
      acc2[nt] = __builtin_amdgcn_mfma_f32_16x16x32_f16(sfrag[kk], bf, acc2[nt], 0, 0, 0);
    }
  }

  // W1 fragments for this wave's N-cols [32w,32w+32): AGPR-pinned, no remat
  f16x8 bw[2][8];
  #pragma unroll
  for (int nt = 0; nt < 2; ++nt) {
    #pragma unroll
    for (int kk = 0; kk < 8; ++kk) {
      bw[nt][kk] = *(const f16x8*)(W1c + (size_t)((kk * 16 + 2 * w + nt) * 512 + l * 8));
      asm volatile("" : "+a"(bw[nt][kk]));   // park in AGPR (64 total: proven safe)
    }
  }
  float gb1v[2];
  gb1v[0] = gb1[32 * w + lr];
  gb1v[1] = gb1[32 * w + 16 + lr];

  // store phase-2 results as fp16 (C/D layout: col=lr, row=lg*4+r); fold gb0
  #pragma unroll
  for (int nt = 0; nt < 4; ++nt) {
    const int col = 64 * w + 16 * nt + lr;
    #pragma unroll
    for (int r = 0; r < 4; ++r) {
      const int row = lg * 4 + r;
      const float v = acc2[nt][r];
      if (col < 256) A_lds[row * HSTR + col]       = (_Float16)(v + gb0[col]);
      else           C_st[row * HSTR + col - 256]  = (_Float16)v;
    }
  }
  __syncthreads();

  // creg: this wave's produce kk-half (w&1): kk = kh..kh+3 -> 16 VGPR
  const int kh = (w & 1) * 4;
  f16x8 creg[4];
  #pragma unroll
  for (int kq = 0; kq < 4; ++kq)
    creg[kq] = *(const f16x8*)&C_st[lr * HSTR + (kh + kq) * 32 + lg * 8];

  const f16x8 zh = {(_Float16)0, (_Float16)0, (_Float16)0, (_Float16)0,
                    (_Float16)0, (_Float16)0, (_Float16)0, (_Float16)0};
  const int tc = w >> 1;   // tile index this wave co-produces each round

  // prologue: produce round 0 into buf0 (C_st is in buf1 -- untouched; creg
  // is lane-local so no barrier needed between capture and this produce)
  {
    char* tb = buf0 + tc * 8192;
    #pragma unroll
    for (int kq = 0; kq < 4; ++kq) {
      const int kk = kh + kq;
      f16x8 av = *(const f16x8*)&A_lds[tc * HSTR + kk * 32 + lg * 8];  // i = tc
      f16x8 u = __builtin_elementwise_max(av + creg[kq], zh);
      *(f16x8*)(tb + kk * 1024 + l * 16) = u;
    }
  }
  __syncthreads();   // round-0 tiles visible; all creg captured before any
                     // wave can reach round 0's produce-into-buf1 below

  float pp0 = 0.f, pp1 = 0.f;

  #pragma unroll 1
  for (int g = 0; g < 4; ++g) {
    char* cbuf = (g & 1) ? buf1 : buf0;

    // ---- produce round g+1 into the OTHER buffer (no barrier before consume:
    //      issue-interleaves with consume MFMAs on separate pipes) ----
    if (g < 3) {
      char* nb = (g & 1) ? buf0 : buf1;
      const int ip = 4 * (g + 1) + tc;
      char* tb = nb + tc * 8192;
      #pragma unroll
      for (int kq = 0; kq < 4; ++kq) {
        const int kk = kh + kq;
        f16x8 av = *(const f16x8*)&A_lds[ip * HSTR + kk * 32 + lg * 8];
        f16x8 u = __builtin_elementwise_max(av + creg[kq], zh);
        *(f16x8*)(tb + kk * 1024 + l * 16) = u;
      }
    }

    // ---- consume round g: 4 sequential tiles (r15 form: 2 chains/tile) ----
    #pragma unroll
    for (int t = 0; t < 4; ++t) {
      const char* tb = cbuf + t * 8192;
      f32x4 a0 = z4, a1 = z4;
      #pragma unroll
      for (int kk = 0; kk < 8; ++kk) {
        f16x8 uf = *(const f16x8*)(tb + kk * 1024 + l * 16);  // linear sweep
        a0 = __builtin_amdgcn_mfma_f32_16x16x32_f16(uf, bw[0][kk], a0, 0, 0, 0);
        a1 = __builtin_amdgcn_mfma_f32_16x16x32_f16(uf, bw[1][kk], a1, 0, 0, 0);
      }
      const int i = 4 * g + t;
      #pragma unroll
      for (int r = 0; r < 4; ++r) {
        const int row = lg * 4 + r;       // = j
        const float v0 = fmaxf(a0[r] + gb1v[0], 0.f);
        const float v1 = fmaxf(a1[r] + gb1v[1], 0.f);
        pp0 += (row == i) ? 0.f : v0;     // mask the (i,i) filler pair
        pp1 += (row == i) ? 0.f : v1;
      }
    }
    __syncthreads();   // round g consumed everywhere + round g+1 tiles ready
  }

  // reduce the 4 lane-groups (disjoint j subsets, same col), write pooled
  {
    float v = pp0;
    v += __shfl_xor(v, 16);
    v += __shfl_xor(v, 32);
    if (lg == 0) pooled[(size_t)b * 256 + 32 * w + lr] = v;
  }
  {
    float v = pp1;
    v += __shfl_xor(v, 16);
    v += __shfl_xor(v, 32);
    if (lg == 0) pooled[(size_t)b * 256 + 32 * w + 16 + lr] = v;
  }
}

// ---- f-MLP: 256 blocks x 4 batches (all CUs busy; weights L2-resident) ----
__global__ __launch_bounds__(256) void fmlp_kernel(
    const float* __restrict__ pooled,
    const float* __restrict__ fW0, const float* __restrict__ fb0,
    const float* __restrict__ fW1, const float* __restrict__ fb1,
    float* __restrict__ out)
{
  const int tid = threadIdx.x;
  const size_t b0 = (size_t)blockIdx.x * 4;
  __shared__ float pl[4][256];
  __shared__ float h1[4][256];

  #pragma unroll
  for (int q = 0; q < 4; ++q)
    pl[q][tid] = pooled[(b0 + q) * 256 + tid];
  __syncthreads();

  float acc[4] = {0.f, 0.f, 0.f, 0.f};
  #pragma unroll 8
  for (int k = 0; k < 256; ++k) {
    const float wv = fW0[(size_t)k * 256 + tid];
    #pragma unroll
    for (int q = 0; q < 4; ++q) acc[q] = fmaf(pl[q][k], wv, acc[q]);
  }
  #pragma unroll
  for (int q = 0; q < 4; ++q) h1[q][tid] = fmaxf(acc[q] + fb0[tid], 0.f);
  __syncthreads();

  float acc2[4] = {0.f, 0.f, 0.f, 0.f};
  #pragma unroll 8
  for (int k = 0; k < 256; ++k) {
    const float wv = fW1[(size_t)k * 256 + tid];
    #pragma unroll
    for (int q = 0; q < 4; ++q) acc2[q] = fmaf(h1[q][k], wv, acc2[q]);
  }
  #pragma unroll
  for (int q = 0; q < 4; ++q)
    out[(b0 + q) * 256 + tid] = fmaxf(acc2[q] + fb1[tid], 0.f);
}

extern "C" void kernel_launch(void* const* d_in, const int* in_sizes, int n_in,
                              void* d_out, int out_size, void* d_ws, size_t ws_size,
                              hipStream_t stream) {
  const float* state = (const float*)d_in[0];
  const float* gW0   = (const float*)d_in[1];
  const float* gb0   = (const float*)d_in[2];
  const float* gW1   = (const float*)d_in[3];
  const float* gb1   = (const float*)d_in[4];
  const float* fW0   = (const float*)d_in[5];
  const float* fb0   = (const float*)d_in[6];
  const float* fW1   = (const float*)d_in[7];
  const float* fb1   = (const float*)d_in[8];
  float* out = (float*)d_out;

  _Float16* W0c = (_Float16*)d_ws;                      // 65536 fp16 = 128KB
  _Float16* W1c = W0c + 65536;                          // 65536 fp16 = 128KB
  float* pooled = (float*)(W1c + 65536);                // 1024*256 f32 = 1MB

  const int Bn = in_sizes[0] / 2048;  // 1024

  prep_kernel<<<dim3(256), dim3(256), 0, stream>>>(gW0, gW1, W0c, W1c);
  pair_kernel<<<dim3(Bn), dim3(512), 0, stream>>>(state, W0c, gb0, W1c, gb1, pooled);
  fmlp_kernel<<<dim3(Bn / 4), dim3(256), 0, stream>>>(pooled, fW0, fb0, fW1, fb1, out);
}